// Round 1
// baseline (1644.209 us; speedup 1.0000x reference)
//
#include <hip/hip_runtime.h>
#include <cstdint>
#include <cstddef>

#define HID 1024
#define NB 256
#define NCAT 80
#define ROWS (NB*NCAT)   // 20480
#define PADL 511

typedef short short8_t __attribute__((ext_vector_type(8)));
typedef float f32x4_t __attribute__((ext_vector_type(4)));
typedef unsigned short u16;
typedef u16 u16x8_t __attribute__((ext_vector_type(8)));
typedef float f32x4v_t __attribute__((ext_vector_type(4)));

typedef const __attribute__((address_space(1))) unsigned int guint_t;
typedef __attribute__((address_space(3))) unsigned int luint_t;

__device__ __forceinline__ void gl_lds16(const void* g, void* l) {
  __builtin_amdgcn_global_load_lds((guint_t*)g, (luint_t*)l, 16, 0, 0);
}

__device__ __forceinline__ u16 f2bf(float f) {
  unsigned u = __float_as_uint(f);
  u += 0x7fffu + ((u >> 16) & 1u);   // RNE (no NaN in this problem)
  return (u16)(u >> 16);
}
__device__ __forceinline__ float bf2f(u16 s) {
  return __uint_as_float(((unsigned)s) << 16);
}

__device__ __forceinline__ f32x4_t mfma16(short8_t a, short8_t b, f32x4_t c) {
  return __builtin_amdgcn_mfma_f32_16x16x32_bf16(a, b, c, 0, 0, 0);
}

// ---------------- weight fp32 -> bf16 conversion ----------------
__global__ void cvt_w_kernel(const float* __restrict__ W1, const float* __restrict__ Wih,
                             const float* __restrict__ Whh, u16* __restrict__ W1b,
                             u16* __restrict__ Wihb, u16* __restrict__ Whhb) {
  int idx = blockIdx.x * 256 + threadIdx.x;  // each handles 4 floats
  const float* src; u16* dst; int off;
  if (idx < 262144) { src = W1; dst = W1b; off = idx; }
  else if (idx < 1048576) { src = Wih; dst = Wihb; off = idx - 262144; }
  else { src = Whh; dst = Whhb; off = idx - 1048576; }
  f32x4v_t v = reinterpret_cast<const f32x4v_t*>(src)[off];
  u16 o0 = f2bf(v[0]), o1 = f2bf(v[1]), o2 = f2bf(v[2]), o3 = f2bf(v[3]);
  u16* d = dst + (size_t)off * 4;
  d[0] = o0; d[1] = o1; d[2] = o2; d[3] = o3;
}

// ---------------- iter1 m: m = relu(x * W1[:,511] + b1) ----------------
__global__ void m1_kernel(const float* __restrict__ x, const float* __restrict__ W1,
                          const float* __restrict__ b1, u16* __restrict__ mb) {
  long idx = (long)blockIdx.x * 256 + threadIdx.x;
  long e = idx * 8;
  int r = (int)(e >> 10); int c0 = (int)(e & 1023);
  float xv = x[r];
  u16x8_t o;
#pragma unroll
  for (int j = 0; j < 8; j++) {
    int c = c0 + j;
    float v = xv * W1[(size_t)c * 1024 + PADL] + b1[c];
    o[j] = f2bf(v > 0.f ? v : 0.f);
  }
  *reinterpret_cast<u16x8_t*>(mb + e) = o;
}

// ---------------- per-batch segment sum over 80 rows ----------------
__global__ void seg_sum_kernel(const u16* __restrict__ mb, float* __restrict__ S) {
  int c = blockIdx.x * 256 + threadIdx.x;
  int b = blockIdx.y;
  const u16* p = mb + (size_t)b * NCAT * 1024 + c;
  float s = 0.f;
#pragma unroll 4
  for (int n = 0; n < NCAT; n++) s += bf2f(p[(size_t)n * 1024]);
  S[(size_t)b * 1024 + c] = s;
}

// ---------------- msg = (S - m)/79, in place ----------------
__global__ void msg_kernel(u16* __restrict__ mb, const float* __restrict__ S) {
  long idx = (long)blockIdx.x * 256 + threadIdx.x;
  long e = idx * 8;
  int r = (int)(e >> 10); int b = r / NCAT; int c0 = (int)(e & 1023);
  u16x8_t v = *reinterpret_cast<u16x8_t*>(mb + e);
  const float inv = 1.0f / (NCAT - 1);
#pragma unroll
  for (int j = 0; j < 8; j++) {
    float m = bf2f(v[j]);
    float s = S[(size_t)b * 1024 + c0 + j];
    v[j] = f2bf((s - m) * inv);
  }
  *reinterpret_cast<u16x8_t*>(mb + e) = v;
}

// ---------------- m GEMM (iters 2,3): m = relu(h @ W1^T + b1) -> bf16 ----------------
__launch_bounds__(256)
__global__ void gemm_m_kernel(const u16* __restrict__ hb, const u16* __restrict__ W1b,
                              const float* __restrict__ b1, u16* __restrict__ mb) {
  __shared__ __attribute__((aligned(128))) char lds[16384];
  const int tid = threadIdx.x;
  const int rb = blockIdx.x, nb = blockIdx.y;
  const int wid = tid >> 6, lane = tid & 63;
  const int wr = wid >> 1, wc = wid & 1;
  const int lr = lane & 15, ls = lane >> 4;
  f32x4_t acc[4][4];
  f32x4_t z4 = {0.f, 0.f, 0.f, 0.f};
#pragma unroll
  for (int m2 = 0; m2 < 4; m2++)
#pragma unroll
    for (int n2 = 0; n2 < 4; n2++) acc[m2][n2] = z4;

  for (int kb = 0; kb < 32; kb++) {
#pragma unroll
    for (int i = 0; i < 4; i++) {
      int c = tid + i * 256;
      const char* src;
      if (c < 512) {
        int r = c >> 2, s = c & 3;
        src = (const char*)hb + (((size_t)(rb * 128 + r)) * 1024 + kb * 32) * 2 + s * 16;
      } else {
        int w = c - 512; int r = w >> 2, s = w & 3;
        src = (const char*)W1b + (((size_t)(nb * 128 + r)) * 1024 + kb * 32) * 2 + s * 16;
      }
      gl_lds16(src, lds + c * 16);
    }
    __syncthreads();
    short8_t a[4], bw[4];
#pragma unroll
    for (int m2 = 0; m2 < 4; m2++)
      a[m2] = *reinterpret_cast<const short8_t*>(lds + ((wr * 64 + m2 * 16 + lr) * 64 + ls * 16));
#pragma unroll
    for (int n2 = 0; n2 < 4; n2++)
      bw[n2] = *reinterpret_cast<const short8_t*>(lds + 8192 + ((wc * 64 + n2 * 16 + lr) * 64 + ls * 16));
#pragma unroll
    for (int m2 = 0; m2 < 4; m2++)
#pragma unroll
      for (int n2 = 0; n2 < 4; n2++)
        acc[m2][n2] = mfma16(a[m2], bw[n2], acc[m2][n2]);
    __syncthreads();
  }
#pragma unroll
  for (int m2 = 0; m2 < 4; m2++)
#pragma unroll
    for (int n2 = 0; n2 < 4; n2++) {
      int col = nb * 128 + wc * 64 + n2 * 16 + lr;
      float bias = b1[col];
#pragma unroll
      for (int j = 0; j < 4; j++) {
        int gr = rb * 128 + wr * 64 + m2 * 16 + ls * 4 + j;
        float v = acc[m2][n2][j] + bias;
        mb[(size_t)gr * 1024 + col] = f2bf(v > 0.f ? v : 0.f);
      }
    }
}

// ---------------- fused gates GEMM + GRU ----------------
// Per block: 128 rows x 64 hidden cols. acc_r/z get msg@Wih + h@Whh summed in place;
// acc_in, acc_hn kept separate. Epilogue does sigmoid/tanh/GRU update, writes
// hidden fp32 (in place) + bf16 (ping-pong).
template <int FIRST>
__launch_bounds__(512)
__global__ void gru_kernel(const u16* __restrict__ msgb, const u16* __restrict__ hbin,
                           const u16* __restrict__ Wihb, const u16* __restrict__ Whhb,
                           const float* __restrict__ bih, const float* __restrict__ bhh,
                           const float* __restrict__ x, const float* __restrict__ WhhF,
                           float* __restrict__ hf, u16* __restrict__ hbout) {
  __shared__ __attribute__((aligned(128))) char lds[40960];
  const int tid = threadIdx.x;
  const int rb = blockIdx.x;
  const int hb0 = blockIdx.y * 64;
  const int wid = tid >> 6, lane = tid & 63;
  const int wr = wid >> 1, wc = wid & 1;
  const int lr = lane & 15, ls = lane >> 4;

  f32x4_t ar[2][2], az[2][2], ain[2][2], ahn[2][2];
  f32x4_t z4 = {0.f, 0.f, 0.f, 0.f};
#pragma unroll
  for (int m2 = 0; m2 < 2; m2++)
#pragma unroll
    for (int n2 = 0; n2 < 2; n2++) { ar[m2][n2] = z4; az[m2][n2] = z4; ain[m2][n2] = z4; ahn[m2][n2] = z4; }

  const int NCHUNK = FIRST ? 1280 : 2560;
  for (int kb = 0; kb < 32; kb++) {
    for (int c = tid; c < NCHUNK; c += 512) {
      const char* src; int dst;
      if (FIRST) {
        if (c < 512) {
          int r = c >> 2, s = c & 3;
          src = (const char*)msgb + (((size_t)(rb * 128 + r)) * 1024 + kb * 32) * 2 + s * 16;
          dst = c * 16;
        } else {
          int w = c - 512; int strip = w >> 8; int r = (w >> 2) & 63; int s = w & 3;
          int wrow = strip * 1024 + hb0 + r;
          src = (const char*)Wihb + (((size_t)wrow) * 1024 + kb * 32) * 2 + s * 16;
          dst = 16384 + (c - 512) * 16;
        }
      } else {
        if (c < 512) {
          int r = c >> 2, s = c & 3;
          src = (const char*)msgb + (((size_t)(rb * 128 + r)) * 1024 + kb * 32) * 2 + s * 16;
          dst = c * 16;
        } else if (c < 1024) {
          int w = c - 512; int r = w >> 2, s = w & 3;
          src = (const char*)hbin + (((size_t)(rb * 128 + r)) * 1024 + kb * 32) * 2 + s * 16;
          dst = c * 16;
        } else {
          int w = c - 1024; int strip = w >> 8; int r = (w >> 2) & 63; int s = w & 3;
          int gate = strip % 3;
          const u16* Wp = (strip < 3) ? Wihb : Whhb;
          int wrow = gate * 1024 + hb0 + r;
          src = (const char*)Wp + (((size_t)wrow) * 1024 + kb * 32) * 2 + s * 16;
          dst = c * 16;
        }
      }
      gl_lds16(src, lds + dst);
    }
    __syncthreads();

    short8_t amsg[2], ah[2], bw[6][2];
#pragma unroll
    for (int m2 = 0; m2 < 2; m2++) {
      amsg[m2] = *reinterpret_cast<const short8_t*>(lds + ((wr * 32 + m2 * 16 + lr) * 64 + ls * 16));
      if (!FIRST)
        ah[m2] = *reinterpret_cast<const short8_t*>(lds + 8192 + ((wr * 32 + m2 * 16 + lr) * 64 + ls * 16));
    }
    const int NS = FIRST ? 3 : 6;
    for (int st = 0; st < NS; st++)
#pragma unroll
      for (int n2 = 0; n2 < 2; n2++)
        bw[st][n2] = *reinterpret_cast<const short8_t*>(lds + 16384 + st * 4096 + ((wc * 32 + n2 * 16 + lr) * 64 + ls * 16));

#pragma unroll
    for (int m2 = 0; m2 < 2; m2++)
#pragma unroll
      for (int n2 = 0; n2 < 2; n2++) {
        ar[m2][n2] = mfma16(amsg[m2], bw[0][n2], ar[m2][n2]);
        az[m2][n2] = mfma16(amsg[m2], bw[1][n2], az[m2][n2]);
        ain[m2][n2] = mfma16(amsg[m2], bw[2][n2], ain[m2][n2]);
        if (!FIRST) {
          ar[m2][n2] = mfma16(ah[m2], bw[3][n2], ar[m2][n2]);
          az[m2][n2] = mfma16(ah[m2], bw[4][n2], az[m2][n2]);
          ahn[m2][n2] = mfma16(ah[m2], bw[5][n2], ahn[m2][n2]);
        }
      }
    __syncthreads();
  }

  // epilogue: GRU update
#pragma unroll
  for (int n2 = 0; n2 < 2; n2++) {
    int ch = hb0 + wc * 32 + n2 * 16 + lr;
    float br_ = bih[ch] + bhh[ch];
    float bz_ = bih[1024 + ch] + bhh[1024 + ch];
    float bin_ = bih[2048 + ch];
    float bhn_ = bhh[2048 + ch];
    float wr511 = 0.f, wz511 = 0.f, wn511 = 0.f;
    if (FIRST) {
      wr511 = WhhF[(size_t)ch * 1024 + PADL];
      wz511 = WhhF[(size_t)(1024 + ch) * 1024 + PADL];
      wn511 = WhhF[(size_t)(2048 + ch) * 1024 + PADL];
    }
#pragma unroll
    for (int m2 = 0; m2 < 2; m2++)
#pragma unroll
      for (int j = 0; j < 4; j++) {
        int gr = rb * 128 + wr * 32 + m2 * 16 + ls * 4 + j;
        float vr = ar[m2][n2][j] + br_;
        float vz = az[m2][n2][j] + bz_;
        float vin = ain[m2][n2][j] + bin_;
        float vhn, hold;
        if (FIRST) {
          float xv = x[gr];
          vr += xv * wr511;
          vz += xv * wz511;
          vhn = xv * wn511 + bhn_;
          hold = (ch == PADL) ? xv : 0.f;
        } else {
          vhn = ahn[m2][n2][j] + bhn_;
          hold = hf[(size_t)gr * 1024 + ch];
        }
        float rg = 1.f / (1.f + __expf(-vr));
        float zg = 1.f / (1.f + __expf(-vz));
        float ng = tanhf(vin + rg * vhn);
        float hnew = (1.f - zg) * ng + zg * hold;
        hf[(size_t)gr * 1024 + ch] = hnew;
        hbout[(size_t)gr * 1024 + ch] = f2bf(hnew);
      }
  }
}

// ---------------- out = h . w_s + b_s ----------------
__global__ void out_proj_kernel(const float* __restrict__ hf, const float* __restrict__ wsv,
                                const float* __restrict__ bs, float* __restrict__ out) {
  int row = blockIdx.x * 4 + (threadIdx.x >> 6);
  int lane = threadIdx.x & 63;
  const float* p = hf + (size_t)row * 1024;
  float s = 0.f;
#pragma unroll
  for (int t = 0; t < 16; t++) s += p[lane + t * 64] * wsv[lane + t * 64];
#pragma unroll
  for (int off = 32; off; off >>= 1) s += __shfl_down(s, off);
  if (lane == 0) out[row] = s + bs[0];
}

extern "C" void kernel_launch(void* const* d_in, const int* in_sizes, int n_in,
                              void* d_out, int out_size, void* d_ws, size_t ws_size,
                              hipStream_t stream) {
  const float* x = (const float*)d_in[0];
  const float* W1 = (const float*)d_in[1];
  const float* b1 = (const float*)d_in[2];
  const float* Wih = (const float*)d_in[3];
  const float* Whh = (const float*)d_in[4];
  const float* bih = (const float*)d_in[5];
  const float* bhh = (const float*)d_in[6];
  const float* wsv = (const float*)d_in[7];
  const float* bs = (const float*)d_in[8];
  float* out = (float*)d_out;

  char* wsp = (char*)d_ws;
  size_t off = 0;
  auto alloc = [&](size_t bytes) { void* p = wsp + off; off += (bytes + 255) & ~(size_t)255; return p; };
  float* hf = (float*)alloc((size_t)ROWS * 1024 * 4);
  u16* hbA = (u16*)alloc((size_t)ROWS * 1024 * 2);
  u16* hbB = (u16*)alloc((size_t)ROWS * 1024 * 2);
  u16* mb = (u16*)alloc((size_t)ROWS * 1024 * 2);
  float* S = (float*)alloc((size_t)NB * 1024 * 4);
  u16* W1b = (u16*)alloc((size_t)1024 * 1024 * 2);
  u16* Wihb = (u16*)alloc((size_t)3072 * 1024 * 2);
  u16* Whhb = (u16*)alloc((size_t)3072 * 1024 * 2);

  cvt_w_kernel<<<7168, 256, 0, stream>>>(W1, Wih, Whh, W1b, Wihb, Whhb);

  // ---- iteration 1 (rank-1 hidden state, specialized) ----
  m1_kernel<<<10240, 256, 0, stream>>>(x, W1, b1, mb);
  seg_sum_kernel<<<dim3(4, NB), 256, 0, stream>>>(mb, S);
  msg_kernel<<<10240, 256, 0, stream>>>(mb, S);
  gru_kernel<1><<<dim3(160, 16), 512, 0, stream>>>(mb, nullptr, Wihb, Whhb, bih, bhh, x, Whh, hf, hbA);

  // ---- iterations 2..T ----
  for (int it = 1; it < 3; it++) {
    u16* hin = (it & 1) ? hbA : hbB;
    u16* hout = (it & 1) ? hbB : hbA;
    gemm_m_kernel<<<dim3(160, 8), 256, 0, stream>>>(hin, W1b, b1, mb);
    seg_sum_kernel<<<dim3(4, NB), 256, 0, stream>>>(mb, S);
    msg_kernel<<<10240, 256, 0, stream>>>(mb, S);
    gru_kernel<0><<<dim3(160, 16), 512, 0, stream>>>(mb, hin, Wihb, Whhb, bih, bhh, x, Whh, hf, hout);
  }

  out_proj_kernel<<<5120, 256, 0, stream>>>(hf, wsv, bs, out);
}

// Round 2
// 1036.961 us; speedup vs baseline: 1.5856x; 1.5856x over previous
//
#include <hip/hip_runtime.h>
#include <cstdint>
#include <cstddef>

#define HID 1024
#define NB 256
#define NCAT 80
#define ROWS (NB*NCAT)   // 20480
#define PADL 511

typedef short short8_t __attribute__((ext_vector_type(8)));
typedef float f32x4_t __attribute__((ext_vector_type(4)));
typedef unsigned short u16;
typedef u16 u16x8_t __attribute__((ext_vector_type(8)));
typedef u16 u16x4_t __attribute__((ext_vector_type(4)));
typedef float f32x4v_t __attribute__((ext_vector_type(4)));

typedef const __attribute__((address_space(1))) unsigned int guint_t;
typedef __attribute__((address_space(3))) unsigned int luint_t;

__device__ __forceinline__ void gl_lds16(const void* g, void* l) {
  __builtin_amdgcn_global_load_lds((guint_t*)g, (luint_t*)l, 16, 0, 0);
}

__device__ __forceinline__ u16 f2bf(float f) {
  unsigned u = __float_as_uint(f);
  u += 0x7fffu + ((u >> 16) & 1u);   // RNE (no NaN in this problem)
  return (u16)(u >> 16);
}
__device__ __forceinline__ float bf2f(u16 s) {
  return __uint_as_float(((unsigned)s) << 16);
}

__device__ __forceinline__ f32x4_t mfma16(short8_t a, short8_t b, f32x4_t c) {
  return __builtin_amdgcn_mfma_f32_16x16x32_bf16(a, b, c, 0, 0, 0);
}

// ---------------- weight fp32 -> bf16 conversion ----------------
__global__ void cvt_w_kernel(const float* __restrict__ W1, const float* __restrict__ Wih,
                             const float* __restrict__ Whh, u16* __restrict__ W1b,
                             u16* __restrict__ Wihb, u16* __restrict__ Whhb) {
  int idx = blockIdx.x * 256 + threadIdx.x;  // each handles 4 floats
  const float* src; u16* dst; int off;
  if (idx < 262144) { src = W1; dst = W1b; off = idx; }
  else if (idx < 1048576) { src = Wih; dst = Wihb; off = idx - 262144; }
  else { src = Whh; dst = Whhb; off = idx - 1048576; }
  f32x4v_t v = reinterpret_cast<const f32x4v_t*>(src)[off];
  u16 o0 = f2bf(v[0]), o1 = f2bf(v[1]), o2 = f2bf(v[2]), o3 = f2bf(v[3]);
  u16* d = dst + (size_t)off * 4;
  d[0] = o0; d[1] = o1; d[2] = o2; d[3] = o3;
}

// ---------------- iter1 m: m = relu(x * W1[:,511] + b1) ----------------
__global__ void m1_kernel(const float* __restrict__ x, const float* __restrict__ W1,
                          const float* __restrict__ b1, u16* __restrict__ mb) {
  long idx = (long)blockIdx.x * 256 + threadIdx.x;
  long e = idx * 8;
  int r = (int)(e >> 10); int c0 = (int)(e & 1023);
  float xv = x[r];
  u16x8_t o;
#pragma unroll
  for (int j = 0; j < 8; j++) {
    int c = c0 + j;
    float v = xv * W1[(size_t)c * 1024 + PADL] + b1[c];
    o[j] = f2bf(v > 0.f ? v : 0.f);
  }
  *reinterpret_cast<u16x8_t*>(mb + e) = o;
}

// ---------------- fused: per-batch segment sum + msg = (S - m)/79 in place ----------------
// Each thread owns 4 columns of one batch entirely -> no cross-thread dependency.
__global__ void seg_msg_kernel(u16* __restrict__ mb) {
  int b = blockIdx.x;
  int c0 = blockIdx.y * 512 + threadIdx.x * 4;
  u16* base = mb + (size_t)b * (NCAT * 1024) + c0;
  float s0 = 0.f, s1 = 0.f, s2 = 0.f, s3 = 0.f;
#pragma unroll 4
  for (int n = 0; n < NCAT; n++) {
    u16x4_t v = *reinterpret_cast<const u16x4_t*>(base + (size_t)n * 1024);
    s0 += bf2f(v[0]); s1 += bf2f(v[1]); s2 += bf2f(v[2]); s3 += bf2f(v[3]);
  }
  const float inv = 1.0f / (NCAT - 1);
#pragma unroll 4
  for (int n = 0; n < NCAT; n++) {
    u16x4_t v = *reinterpret_cast<const u16x4_t*>(base + (size_t)n * 1024);
    u16x4_t o;
    o[0] = f2bf((s0 - bf2f(v[0])) * inv);
    o[1] = f2bf((s1 - bf2f(v[1])) * inv);
    o[2] = f2bf((s2 - bf2f(v[2])) * inv);
    o[3] = f2bf((s3 - bf2f(v[3])) * inv);
    *reinterpret_cast<u16x4_t*>(base + (size_t)n * 1024) = o;
  }
}

// ---------------- m GEMM (iters 2,3): m = relu(h @ W1^T + b1) -> bf16 ----------------
// 128x128 tile, BK=32, double-buffered + prefetch + XOR swizzle (both-sides).
__device__ __forceinline__ void gm_stage(int kb, char* dstbase, const u16* hb,
                                         const u16* W1b, int rb, int nb, int tid) {
#pragma unroll
  for (int i = 0; i < 4; i++) {
    int c = tid + i * 256;
    const u16* src;
    if (c < 512) {
      int r = c >> 2, s = c & 3;
      int sp = s ^ ((r >> 1) & 3);
      src = hb + ((size_t)(rb * 128 + r)) * 1024 + kb * 32 + sp * 8;
    } else {
      int w = c - 512; int r = w >> 2, s = w & 3;
      int sp = s ^ ((r >> 1) & 3);
      src = W1b + ((size_t)(nb * 128 + r)) * 1024 + kb * 32 + sp * 8;
    }
    gl_lds16(src, dstbase + c * 16);
  }
}

__launch_bounds__(256, 4)
__global__ void gemm_m_kernel(const u16* __restrict__ hb, const u16* __restrict__ W1b,
                              const float* __restrict__ b1, u16* __restrict__ mb) {
  __shared__ __attribute__((aligned(128))) char lds[32768];
  const int tid = threadIdx.x;
  const int rb = blockIdx.x, nb = blockIdx.y;
  const int wid = tid >> 6, lane = tid & 63;
  const int wr = wid >> 1, wc = wid & 1;
  const int lr = lane & 15, ls = lane >> 4;
  const int swoff = (ls ^ ((lr >> 1) & 3)) * 16;
  f32x4_t acc[4][4];
  f32x4_t z4 = {0.f, 0.f, 0.f, 0.f};
#pragma unroll
  for (int m2 = 0; m2 < 4; m2++)
#pragma unroll
    for (int n2 = 0; n2 < 4; n2++) acc[m2][n2] = z4;

  gm_stage(0, lds, hb, W1b, rb, nb, tid);
  __syncthreads();
  int cur = 0;
  for (int kb = 0; kb < 32; kb++) {
    char* bc = lds + cur * 16384;
    if (kb + 1 < 32) gm_stage(kb + 1, lds + (cur ^ 1) * 16384, hb, W1b, rb, nb, tid);
    short8_t a[4], bw[4];
#pragma unroll
    for (int m2 = 0; m2 < 4; m2++) {
      int row = wr * 64 + m2 * 16 + lr;
      a[m2] = *reinterpret_cast<const short8_t*>(bc + row * 64 + swoff);
    }
#pragma unroll
    for (int n2 = 0; n2 < 4; n2++) {
      int r = wc * 64 + n2 * 16 + lr;
      bw[n2] = *reinterpret_cast<const short8_t*>(bc + 8192 + r * 64 + swoff);
    }
#pragma unroll
    for (int m2 = 0; m2 < 4; m2++)
#pragma unroll
      for (int n2 = 0; n2 < 4; n2++)
        acc[m2][n2] = mfma16(a[m2], bw[n2], acc[m2][n2]);
    __syncthreads();
    cur ^= 1;
  }
#pragma unroll
  for (int m2 = 0; m2 < 4; m2++)
#pragma unroll
    for (int n2 = 0; n2 < 4; n2++) {
      int col = nb * 128 + wc * 64 + n2 * 16 + lr;
      float bias = b1[col];
#pragma unroll
      for (int j = 0; j < 4; j++) {
        int gr = rb * 128 + wr * 64 + m2 * 16 + ls * 4 + j;
        float v = acc[m2][n2][j] + bias;
        mb[(size_t)gr * 1024 + col] = f2bf(v > 0.f ? v : 0.f);
      }
    }
}

// ---------------- fused gates GEMM + GRU, unified K (msg then h) ----------------
// Per block: 128 rows x 64 hidden cols x 3 gates. K-iters 0..31 stage msg+Wih,
// 32..63 stage h+Whh. r,z accumulate across all 64; n splits into ain/ahn.
// Double-buffered (2 x 20KB), prefetch-before-compute, XOR-swizzled.
template <int FIRST>
__device__ __forceinline__ void gru_stage(int kb, char* dstbase,
    const u16* msgb, const u16* hbin, const u16* Wihb, const u16* Whhb,
    int rb, int hb0, int tid) {
  const u16* Ap; const u16* Wp; int kk;
  if (FIRST) { Ap = msgb; Wp = Wihb; kk = kb; }
  else if (kb < 32) { Ap = msgb; Wp = Wihb; kk = kb; }
  else { Ap = hbin; Wp = Whhb; kk = kb - 32; }
#pragma unroll
  for (int i = 0; i < 3; i++) {
    int c = tid + i * 512;
    if (c < 1280) {
      const u16* src; char* dst;
      if (c < 512) {
        int r = c >> 2, s = c & 3;
        int sp = s ^ ((r >> 1) & 3);
        src = Ap + ((size_t)(rb * 128 + r)) * 1024 + kk * 32 + sp * 8;
        dst = dstbase + c * 16;
      } else {
        int w = c - 512;
        int g = w >> 8, r = (w >> 2) & 63, s = w & 3;
        int sp = s ^ ((r >> 1) & 3);
        src = Wp + ((size_t)(g * 1024 + hb0 + r)) * 1024 + kk * 32 + sp * 8;
        dst = dstbase + 8192 + w * 16;
      }
      gl_lds16(src, dst);
    }
  }
}

template <int FIRST>
__launch_bounds__(512, 4)
__global__ void gru_kernel(const u16* __restrict__ msgb, const u16* __restrict__ hbin,
                           const u16* __restrict__ Wihb, const u16* __restrict__ Whhb,
                           const float* __restrict__ bih, const float* __restrict__ bhh,
                           const float* __restrict__ x, const float* __restrict__ WhhF,
                           float* __restrict__ hf, u16* __restrict__ hbout) {
  __shared__ __attribute__((aligned(128))) char lds[40960];
  const int tid = threadIdx.x;
  const int rb = blockIdx.x;
  const int hb0 = blockIdx.y * 64;
  const int wid = tid >> 6, lane = tid & 63;
  const int wr = wid >> 1, wc = wid & 1;    // wr 0..3 (32 rows each), wc 0..1 (32 cols each)
  const int lr = lane & 15, ls = lane >> 4;
  const int swoff = (ls ^ ((lr >> 1) & 3)) * 16;

  f32x4_t ar[2][2], az[2][2], ain[2][2], ahn[2][2];
  f32x4_t z4 = {0.f, 0.f, 0.f, 0.f};
#pragma unroll
  for (int m2 = 0; m2 < 2; m2++)
#pragma unroll
    for (int n2 = 0; n2 < 2; n2++) { ar[m2][n2] = z4; az[m2][n2] = z4; ain[m2][n2] = z4; ahn[m2][n2] = z4; }

  const int NK = FIRST ? 32 : 64;
  gru_stage<FIRST>(0, lds, msgb, hbin, Wihb, Whhb, rb, hb0, tid);
  __syncthreads();
  int cur = 0;
  for (int kb = 0; kb < NK; kb++) {
    char* bc = lds + cur * 20480;
    if (kb + 1 < NK)
      gru_stage<FIRST>(kb + 1, lds + (cur ^ 1) * 20480, msgb, hbin, Wihb, Whhb, rb, hb0, tid);

    short8_t a[2], br_[2], bz_[2], bn_[2];
#pragma unroll
    for (int m2 = 0; m2 < 2; m2++) {
      int row = wr * 32 + m2 * 16 + lr;
      a[m2] = *reinterpret_cast<const short8_t*>(bc + row * 64 + swoff);
    }
#pragma unroll
    for (int n2 = 0; n2 < 2; n2++) {
      int r = wc * 32 + n2 * 16 + lr;
      br_[n2] = *reinterpret_cast<const short8_t*>(bc + 8192 + r * 64 + swoff);
      bz_[n2] = *reinterpret_cast<const short8_t*>(bc + 12288 + r * 64 + swoff);
      bn_[n2] = *reinterpret_cast<const short8_t*>(bc + 16384 + r * 64 + swoff);
    }
    const bool second = (!FIRST) && (kb >= 32);
#pragma unroll
    for (int m2 = 0; m2 < 2; m2++)
#pragma unroll
      for (int n2 = 0; n2 < 2; n2++) {
        ar[m2][n2] = mfma16(a[m2], br_[n2], ar[m2][n2]);
        az[m2][n2] = mfma16(a[m2], bz_[n2], az[m2][n2]);
        if (second) ahn[m2][n2] = mfma16(a[m2], bn_[n2], ahn[m2][n2]);
        else        ain[m2][n2] = mfma16(a[m2], bn_[n2], ain[m2][n2]);
      }
    __syncthreads();
    cur ^= 1;
  }

  // epilogue: GRU update
#pragma unroll
  for (int n2 = 0; n2 < 2; n2++) {
    int ch = hb0 + wc * 32 + n2 * 16 + lr;
    float br_ = bih[ch] + bhh[ch];
    float bz_ = bih[1024 + ch] + bhh[1024 + ch];
    float bin_ = bih[2048 + ch];
    float bhn_ = bhh[2048 + ch];
    float wr511 = 0.f, wz511 = 0.f, wn511 = 0.f;
    if (FIRST) {
      wr511 = WhhF[(size_t)ch * 1024 + PADL];
      wz511 = WhhF[(size_t)(1024 + ch) * 1024 + PADL];
      wn511 = WhhF[(size_t)(2048 + ch) * 1024 + PADL];
    }
#pragma unroll
    for (int m2 = 0; m2 < 2; m2++)
#pragma unroll
      for (int j = 0; j < 4; j++) {
        int gr = rb * 128 + wr * 32 + m2 * 16 + ls * 4 + j;
        float vr = ar[m2][n2][j] + br_;
        float vz = az[m2][n2][j] + bz_;
        float vin = ain[m2][n2][j] + bin_;
        float vhn, hold;
        if (FIRST) {
          float xv = x[gr];
          vr += xv * wr511;
          vz += xv * wz511;
          vhn = xv * wn511 + bhn_;
          hold = (ch == PADL) ? xv : 0.f;
        } else {
          vhn = ahn[m2][n2][j] + bhn_;
          hold = hf[(size_t)gr * 1024 + ch];
        }
        float rg = 1.f / (1.f + __expf(-vr));
        float zg = 1.f / (1.f + __expf(-vz));
        float ng = tanhf(vin + rg * vhn);
        float hnew = (1.f - zg) * ng + zg * hold;
        hf[(size_t)gr * 1024 + ch] = hnew;
        hbout[(size_t)gr * 1024 + ch] = f2bf(hnew);
      }
  }
}

// ---------------- out = h . w_s + b_s ----------------
__global__ void out_proj_kernel(const float* __restrict__ hf, const float* __restrict__ wsv,
                                const float* __restrict__ bs, float* __restrict__ out) {
  int row = blockIdx.x * 4 + (threadIdx.x >> 6);
  int lane = threadIdx.x & 63;
  const float* p = hf + (size_t)row * 1024;
  float s = 0.f;
#pragma unroll
  for (int t = 0; t < 16; t++) s += p[lane + t * 64] * wsv[lane + t * 64];
#pragma unroll
  for (int off = 32; off; off >>= 1) s += __shfl_down(s, off);
  if (lane == 0) out[row] = s + bs[0];
}

extern "C" void kernel_launch(void* const* d_in, const int* in_sizes, int n_in,
                              void* d_out, int out_size, void* d_ws, size_t ws_size,
                              hipStream_t stream) {
  const float* x = (const float*)d_in[0];
  const float* W1 = (const float*)d_in[1];
  const float* b1 = (const float*)d_in[2];
  const float* Wih = (const float*)d_in[3];
  const float* Whh = (const float*)d_in[4];
  const float* bih = (const float*)d_in[5];
  const float* bhh = (const float*)d_in[6];
  const float* wsv = (const float*)d_in[7];
  const float* bs = (const float*)d_in[8];
  float* out = (float*)d_out;

  char* wsp = (char*)d_ws;
  size_t off = 0;
  auto alloc = [&](size_t bytes) { void* p = wsp + off; off += (bytes + 255) & ~(size_t)255; return p; };
  float* hf = (float*)alloc((size_t)ROWS * 1024 * 4);
  u16* hbA = (u16*)alloc((size_t)ROWS * 1024 * 2);
  u16* hbB = (u16*)alloc((size_t)ROWS * 1024 * 2);
  u16* mb = (u16*)alloc((size_t)ROWS * 1024 * 2);
  u16* W1b = (u16*)alloc((size_t)1024 * 1024 * 2);
  u16* Wihb = (u16*)alloc((size_t)3072 * 1024 * 2);
  u16* Whhb = (u16*)alloc((size_t)3072 * 1024 * 2);

  cvt_w_kernel<<<7168, 256, 0, stream>>>(W1, Wih, Whh, W1b, Wihb, Whhb);

  // ---- iteration 1 (rank-1 hidden state, specialized) ----
  m1_kernel<<<10240, 256, 0, stream>>>(x, W1, b1, mb);
  seg_msg_kernel<<<dim3(NB, 2), 128, 0, stream>>>(mb);
  gru_kernel<1><<<dim3(160, 16), 512, 0, stream>>>(mb, nullptr, Wihb, Whhb, bih, bhh, x, Whh, hf, hbA);

  // ---- iterations 2..T ----
  for (int it = 1; it < 3; it++) {
    u16* hin = (it & 1) ? hbA : hbB;
    u16* hout = (it & 1) ? hbB : hbA;
    gemm_m_kernel<<<dim3(160, 8), 256, 0, stream>>>(hin, W1b, b1, mb);
    seg_msg_kernel<<<dim3(NB, 2), 128, 0, stream>>>(mb);
    gru_kernel<0><<<dim3(160, 16), 512, 0, stream>>>(mb, hin, Wihb, Whhb, bih, bhh, x, Whh, hf, hout);
  }

  out_proj_kernel<<<5120, 256, 0, stream>>>(hf, wsv, bs, out);
}

// Round 3
// 981.397 us; speedup vs baseline: 1.6754x; 1.0566x over previous
//
#include <hip/hip_runtime.h>
#include <cstdint>
#include <cstddef>

#define HID 1024
#define NB 256
#define NCAT 80
#define ROWS (NB*NCAT)   // 20480
#define PADL 511

typedef short short8_t __attribute__((ext_vector_type(8)));
typedef float f32x4_t __attribute__((ext_vector_type(4)));
typedef unsigned short u16;
typedef u16 u16x8_t __attribute__((ext_vector_type(8)));
typedef u16 u16x4_t __attribute__((ext_vector_type(4)));
typedef float f32x4v_t __attribute__((ext_vector_type(4)));

typedef const __attribute__((address_space(1))) unsigned int guint_t;
typedef __attribute__((address_space(3))) unsigned int luint_t;

__device__ __forceinline__ void gl_lds16(const void* g, void* l) {
  __builtin_amdgcn_global_load_lds((guint_t*)g, (luint_t*)l, 16, 0, 0);
}

__device__ __forceinline__ u16 f2bf(float f) {
  unsigned u = __float_as_uint(f);
  u += 0x7fffu + ((u >> 16) & 1u);   // RNE (no NaN in this problem)
  return (u16)(u >> 16);
}
__device__ __forceinline__ float bf2f(u16 s) {
  return __uint_as_float(((unsigned)s) << 16);
}

__device__ __forceinline__ f32x4_t mfma16(short8_t a, short8_t b, f32x4_t c) {
  return __builtin_amdgcn_mfma_f32_16x16x32_bf16(a, b, c, 0, 0, 0);
}

// ---------------- weight fp32 -> bf16 conversion ----------------
__global__ void cvt_w_kernel(const float* __restrict__ W1, const float* __restrict__ Wih,
                             const float* __restrict__ Whh, u16* __restrict__ W1b,
                             u16* __restrict__ Wihb, u16* __restrict__ Whhb) {
  int idx = blockIdx.x * 256 + threadIdx.x;  // each handles 4 floats
  const float* src; u16* dst; int off;
  if (idx < 262144) { src = W1; dst = W1b; off = idx; }
  else if (idx < 1048576) { src = Wih; dst = Wihb; off = idx - 262144; }
  else { src = Whh; dst = Whhb; off = idx - 1048576; }
  f32x4v_t v = reinterpret_cast<const f32x4v_t*>(src)[off];
  u16 o0 = f2bf(v[0]), o1 = f2bf(v[1]), o2 = f2bf(v[2]), o3 = f2bf(v[3]);
  u16* d = dst + (size_t)off * 4;
  d[0] = o0; d[1] = o1; d[2] = o2; d[3] = o3;
}

// ---------------- iter1 m: m = relu(x * W1[:,511] + b1) ----------------
__global__ void m1_kernel(const float* __restrict__ x, const float* __restrict__ W1,
                          const float* __restrict__ b1, u16* __restrict__ mb) {
  long idx = (long)blockIdx.x * 256 + threadIdx.x;
  long e = idx * 8;
  int r = (int)(e >> 10); int c0 = (int)(e & 1023);
  float xv = x[r];
  u16x8_t o;
#pragma unroll
  for (int j = 0; j < 8; j++) {
    int c = c0 + j;
    float v = xv * W1[(size_t)c * 1024 + PADL] + b1[c];
    o[j] = f2bf(v > 0.f ? v : 0.f);
  }
  *reinterpret_cast<u16x8_t*>(mb + e) = o;
}

// ---------------- fused: per-batch segment sum + msg = (S - m)/79 in place ----------------
__global__ void seg_msg_kernel(u16* __restrict__ mb) {
  int b = blockIdx.x;
  int c0 = blockIdx.y * 512 + threadIdx.x * 4;
  u16* base = mb + (size_t)b * (NCAT * 1024) + c0;
  float s0 = 0.f, s1 = 0.f, s2 = 0.f, s3 = 0.f;
#pragma unroll 4
  for (int n = 0; n < NCAT; n++) {
    u16x4_t v = *reinterpret_cast<const u16x4_t*>(base + (size_t)n * 1024);
    s0 += bf2f(v[0]); s1 += bf2f(v[1]); s2 += bf2f(v[2]); s3 += bf2f(v[3]);
  }
  const float inv = 1.0f / (NCAT - 1);
#pragma unroll 4
  for (int n = 0; n < NCAT; n++) {
    u16x4_t v = *reinterpret_cast<const u16x4_t*>(base + (size_t)n * 1024);
    u16x4_t o;
    o[0] = f2bf((s0 - bf2f(v[0])) * inv);
    o[1] = f2bf((s1 - bf2f(v[1])) * inv);
    o[2] = f2bf((s2 - bf2f(v[2])) * inv);
    o[3] = f2bf((s3 - bf2f(v[3])) * inv);
    *reinterpret_cast<u16x4_t*>(base + (size_t)n * 1024) = o;
  }
}

// ---------------- m GEMM (iters 2,3): m = relu(h @ W1^T + b1) -> bf16 ----------------
__device__ __forceinline__ void gm_stage(int kb, char* dstbase, const u16* hb,
                                         const u16* W1b, int rb, int nb, int tid) {
#pragma unroll
  for (int i = 0; i < 4; i++) {
    int c = tid + i * 256;
    const u16* src;
    if (c < 512) {
      int r = c >> 2, s = c & 3;
      int sp = s ^ ((r >> 1) & 3);
      src = hb + ((size_t)(rb * 128 + r)) * 1024 + kb * 32 + sp * 8;
    } else {
      int w = c - 512; int r = w >> 2, s = w & 3;
      int sp = s ^ ((r >> 1) & 3);
      src = W1b + ((size_t)(nb * 128 + r)) * 1024 + kb * 32 + sp * 8;
    }
    gl_lds16(src, dstbase + c * 16);
  }
}

__launch_bounds__(256, 4)
__global__ void gemm_m_kernel(const u16* __restrict__ hb, const u16* __restrict__ W1b,
                              const float* __restrict__ b1, u16* __restrict__ mb) {
  __shared__ __attribute__((aligned(128))) char lds[32768];
  const int tid = threadIdx.x;
  const int rb = blockIdx.x, nb = blockIdx.y;
  const int wid = tid >> 6, lane = tid & 63;
  const int wr = wid >> 1, wc = wid & 1;
  const int lr = lane & 15, ls = lane >> 4;
  const int swoff = (ls ^ ((lr >> 1) & 3)) * 16;
  f32x4_t acc[4][4];
  f32x4_t z4 = {0.f, 0.f, 0.f, 0.f};
#pragma unroll
  for (int m2 = 0; m2 < 4; m2++)
#pragma unroll
    for (int n2 = 0; n2 < 4; n2++) acc[m2][n2] = z4;

  gm_stage(0, lds, hb, W1b, rb, nb, tid);
  __syncthreads();
  int cur = 0;
  for (int kb = 0; kb < 32; kb++) {
    char* bc = lds + cur * 16384;
    if (kb + 1 < 32) gm_stage(kb + 1, lds + (cur ^ 1) * 16384, hb, W1b, rb, nb, tid);
    short8_t a[4], bw[4];
#pragma unroll
    for (int m2 = 0; m2 < 4; m2++) {
      int row = wr * 64 + m2 * 16 + lr;
      a[m2] = *reinterpret_cast<const short8_t*>(bc + row * 64 + swoff);
    }
#pragma unroll
    for (int n2 = 0; n2 < 4; n2++) {
      int r = wc * 64 + n2 * 16 + lr;
      bw[n2] = *reinterpret_cast<const short8_t*>(bc + 8192 + r * 64 + swoff);
    }
#pragma unroll
    for (int m2 = 0; m2 < 4; m2++)
#pragma unroll
      for (int n2 = 0; n2 < 4; n2++)
        acc[m2][n2] = mfma16(a[m2], bw[n2], acc[m2][n2]);
    __syncthreads();
    cur ^= 1;
  }
#pragma unroll
  for (int m2 = 0; m2 < 4; m2++)
#pragma unroll
    for (int n2 = 0; n2 < 4; n2++) {
      int col = nb * 128 + wc * 64 + n2 * 16 + lr;
      float bias = b1[col];
#pragma unroll
      for (int j = 0; j < 4; j++) {
        int gr = rb * 128 + wr * 64 + m2 * 16 + ls * 4 + j;
        float v = acc[m2][n2][j] + bias;
        mb[(size_t)gr * 1024 + col] = f2bf(v > 0.f ? v : 0.f);
      }
    }
}

// ---------------- fused gates GEMM + GRU ----------------
// BM=256 rows x 64 hidden cols x 3 gates per block. 8 waves as 4M x 2N:
// wave tile 64 rows x 32 cols, M_rep=4, N_rep=2 per gate.
// K split in two segments: seg0 = msg @ Wih (n-gate -> an0),
// seg1 = h @ Whh (n-gate -> an1); r,z accumulate across both.
// Double-buffered LDS (2 x 28KB), prefetch-before-compute, XOR swizzle,
// loop-carried staging pointers (+64B/iter, unroll-folded).
template <int NSEG>   // 1 = first iteration (rank-1 h), 2 = general
__launch_bounds__(512, 2)
__global__ void gru_kernel(const u16* __restrict__ msgb, const u16* __restrict__ hbin,
                           const u16* __restrict__ Wihb, const u16* __restrict__ Whhb,
                           const float* __restrict__ bih, const float* __restrict__ bhh,
                           const float* __restrict__ x, const float* __restrict__ WhhF,
                           float* __restrict__ hf, u16* __restrict__ hbout) {
  __shared__ __attribute__((aligned(128))) char lds[57344];
  const int tid = threadIdx.x;
  const int rb = blockIdx.x;        // 80 row-blocks of 256
  const int hb0 = blockIdx.y * 64;
  const int wid = tid >> 6, lane = tid & 63;
  const int mw = wid >> 1, nw = wid & 1;   // 4M x 2N waves
  const int lr = lane & 15, ls = lane >> 4;
  const int swoff = (ls ^ ((lr >> 1) & 3)) * 16;

  // ---- staging setup: per-thread fixed chunks ----
  // chunk0: A row r0 (0..127)      chunk1: A row 128+r0
  // chunk2: W lrow r0 (0..127)     chunk3 (tid<256): W lrow 128+r0
  const int slot = tid & 3;
  const int r0 = tid >> 2;
  const int sp16 = (slot ^ ((r0 >> 1) & 3)) * 16;   // same for all 4 chunks (rows differ by 128)
  const char* sA0 = (const char*)msgb + ((size_t)(rb * 256 + r0) << 11) + sp16;
  const char* sA1 = (const char*)msgb + ((size_t)(rb * 256 + 128 + r0) << 11) + sp16;
  const int g2 = r0 >> 6, c2 = r0 & 63;
  const char* sW2 = (const char*)Wihb + ((size_t)(g2 * 1024 + hb0 + c2) << 11) + sp16;
  const char* sW3 = (const char*)Wihb + ((size_t)(2048 + hb0 + (r0 & 63)) << 11) + sp16;
  const int d0 = tid * 16, d1 = d0 + 8192, d2 = d0 + 16384, d3 = d0 + 24576;

#define STAGE(BUF) do { \
    gl_lds16(sA0, (BUF) + d0); gl_lds16(sA1, (BUF) + d1); gl_lds16(sW2, (BUF) + d2); \
    if (tid < 256) gl_lds16(sW3, (BUF) + d3); \
    sA0 += 64; sA1 += 64; sW2 += 64; sW3 += 64; } while (0)

  // ---- fragment LDS offsets (constant across iters) ----
  int offA[4], offB[3][2];
#pragma unroll
  for (int m = 0; m < 4; m++) offA[m] = (mw * 64 + m * 16 + lr) * 64 + swoff;
#pragma unroll
  for (int g = 0; g < 3; g++)
#pragma unroll
    for (int n = 0; n < 2; n++)
      offB[g][n] = 16384 + (g * 64 + nw * 32 + n * 16 + lr) * 64 + swoff;

  f32x4_t ar[4][2], az[4][2], an0[4][2], an1[4][2];
  f32x4_t z4 = {0.f, 0.f, 0.f, 0.f};
#pragma unroll
  for (int m = 0; m < 4; m++)
#pragma unroll
    for (int n = 0; n < 2; n++) { ar[m][n] = z4; az[m][n] = z4; an0[m][n] = z4; an1[m][n] = z4; }

#define COMPUTE(BUF, AN) do { \
    short8_t a_[4], bR_[2], bZ_[2], bN_[2]; \
    _Pragma("unroll") for (int m = 0; m < 4; m++) \
      a_[m] = *reinterpret_cast<const short8_t*>((BUF) + offA[m]); \
    _Pragma("unroll") for (int n = 0; n < 2; n++) { \
      bR_[n] = *reinterpret_cast<const short8_t*>((BUF) + offB[0][n]); \
      bZ_[n] = *reinterpret_cast<const short8_t*>((BUF) + offB[1][n]); \
      bN_[n] = *reinterpret_cast<const short8_t*>((BUF) + offB[2][n]); } \
    _Pragma("unroll") for (int m = 0; m < 4; m++) \
    _Pragma("unroll") for (int n = 0; n < 2; n++) { \
      ar[m][n] = mfma16(a_[m], bR_[n], ar[m][n]); \
      az[m][n] = mfma16(a_[m], bZ_[n], az[m][n]); \
      AN[m][n] = mfma16(a_[m], bN_[n], AN[m][n]); } \
  } while (0)

  char* bufA = lds;
  char* bufB = lds + 28672;

  STAGE(bufA);                       // tile 0
  __syncthreads();
  // ---- segment 0: msg @ {Wih_r, Wih_z, Wih_n} ----
  for (int kb = 0; kb < 32; kb += 2) {
    STAGE(bufB);                     // tile kb+1
    COMPUTE(bufA, an0);
    __syncthreads();
    if (kb != 30) {
      STAGE(bufA);                   // tile kb+2
    } else if (NSEG == 2) {
      const ptrdiff_t dA = (const char*)hbin - (const char*)msgb - 2048;
      const ptrdiff_t dW = (const char*)Whhb - (const char*)Wihb - 2048;
      sA0 += dA; sA1 += dA; sW2 += dW; sW3 += dW;
      STAGE(bufA);                   // tile 32 (first of segment 1)
    }
    COMPUTE(bufB, an0);
    __syncthreads();
  }
  // ---- segment 1: h @ {Whh_r, Whh_z, Whh_n} ----
  if (NSEG == 2) {
    for (int kb = 0; kb < 32; kb += 2) {
      STAGE(bufB);
      COMPUTE(bufA, an1);
      __syncthreads();
      if (kb != 30) STAGE(bufA);
      COMPUTE(bufB, an1);
      __syncthreads();
    }
  }
#undef STAGE
#undef COMPUTE

  // ---- epilogue: GRU update ----
#pragma unroll
  for (int n2 = 0; n2 < 2; n2++) {
    int ch = hb0 + nw * 32 + n2 * 16 + lr;
    float br_ = bih[ch] + bhh[ch];
    float bz_ = bih[1024 + ch] + bhh[1024 + ch];
    float bin_ = bih[2048 + ch];
    float bhn_ = bhh[2048 + ch];
    float wr511 = 0.f, wz511 = 0.f, wn511 = 0.f;
    if (NSEG == 1) {
      wr511 = WhhF[(size_t)ch * 1024 + PADL];
      wz511 = WhhF[(size_t)(1024 + ch) * 1024 + PADL];
      wn511 = WhhF[(size_t)(2048 + ch) * 1024 + PADL];
    }
#pragma unroll
    for (int m = 0; m < 4; m++)
#pragma unroll
      for (int j = 0; j < 4; j++) {
        int gr = rb * 256 + mw * 64 + m * 16 + ls * 4 + j;
        float vr = ar[m][n2][j] + br_;
        float vz = az[m][n2][j] + bz_;
        float vin = an0[m][n2][j] + bin_;
        float vhn, hold;
        if (NSEG == 1) {
          float xv = x[gr];
          vr += xv * wr511;
          vz += xv * wz511;
          vhn = xv * wn511 + bhn_;
          hold = (ch == PADL) ? xv : 0.f;
        } else {
          vhn = an1[m][n2][j] + bhn_;
          hold = hf[(size_t)gr * 1024 + ch];
        }
        float rg = 1.f / (1.f + __expf(-vr));
        float zg = 1.f / (1.f + __expf(-vz));
        float ng = tanhf(vin + rg * vhn);
        float hnew = (1.f - zg) * ng + zg * hold;
        hf[(size_t)gr * 1024 + ch] = hnew;
        hbout[(size_t)gr * 1024 + ch] = f2bf(hnew);
      }
  }
}

// ---------------- out = h . w_s + b_s ----------------
__global__ void out_proj_kernel(const float* __restrict__ hf, const float* __restrict__ wsv,
                                const float* __restrict__ bs, float* __restrict__ out) {
  int row = blockIdx.x * 4 + (threadIdx.x >> 6);
  int lane = threadIdx.x & 63;
  const float* p = hf + (size_t)row * 1024;
  float s = 0.f;
#pragma unroll
  for (int t = 0; t < 16; t++) s += p[lane + t * 64] * wsv[lane + t * 64];
#pragma unroll
  for (int off = 32; off; off >>= 1) s += __shfl_down(s, off);
  if (lane == 0) out[row] = s + bs[0];
}

extern "C" void kernel_launch(void* const* d_in, const int* in_sizes, int n_in,
                              void* d_out, int out_size, void* d_ws, size_t ws_size,
                              hipStream_t stream) {
  const float* x = (const float*)d_in[0];
  const float* W1 = (const float*)d_in[1];
  const float* b1 = (const float*)d_in[2];
  const float* Wih = (const float*)d_in[3];
  const float* Whh = (const float*)d_in[4];
  const float* bih = (const float*)d_in[5];
  const float* bhh = (const float*)d_in[6];
  const float* wsv = (const float*)d_in[7];
  const float* bs = (const float*)d_in[8];
  float* out = (float*)d_out;

  char* wsp = (char*)d_ws;
  size_t off = 0;
  auto alloc = [&](size_t bytes) { void* p = wsp + off; off += (bytes + 255) & ~(size_t)255; return p; };
  float* hf = (float*)alloc((size_t)ROWS * 1024 * 4);
  u16* hbA = (u16*)alloc((size_t)ROWS * 1024 * 2);
  u16* hbB = (u16*)alloc((size_t)ROWS * 1024 * 2);
  u16* mb = (u16*)alloc((size_t)ROWS * 1024 * 2);
  u16* W1b = (u16*)alloc((size_t)1024 * 1024 * 2);
  u16* Wihb = (u16*)alloc((size_t)3072 * 1024 * 2);
  u16* Whhb = (u16*)alloc((size_t)3072 * 1024 * 2);

  cvt_w_kernel<<<7168, 256, 0, stream>>>(W1, Wih, Whh, W1b, Wihb, Whhb);

  // ---- iteration 1 (rank-1 hidden state, specialized) ----
  m1_kernel<<<10240, 256, 0, stream>>>(x, W1, b1, mb);
  seg_msg_kernel<<<dim3(NB, 2), 128, 0, stream>>>(mb);
  gru_kernel<1><<<dim3(80, 16), 512, 0, stream>>>(mb, nullptr, Wihb, Whhb, bih, bhh, x, Whh, hf, hbA);

  // ---- iterations 2..T ----
  for (int it = 1; it < 3; it++) {
    u16* hin = (it & 1) ? hbA : hbB;
    u16* hout = (it & 1) ? hbB : hbA;
    gemm_m_kernel<<<dim3(160, 8), 256, 0, stream>>>(hin, W1b, b1, mb);
    seg_msg_kernel<<<dim3(NB, 2), 128, 0, stream>>>(mb);
    gru_kernel<0 + 2><<<dim3(80, 16), 512, 0, stream>>>(mb, hin, Wihb, Whhb, bih, bhh, x, Whh, hf, hout);
  }

  out_proj_kernel<<<5120, 256, 0, stream>>>(hf, wsv, bs, out);
}